// Round 4
// baseline (954.740 us; speedup 1.0000x reference)
//
#include <hip/hip_runtime.h>

#define MDIM 4096
#define KDIM 4096
#define NDIM 14336

typedef __attribute__((ext_vector_type(8))) short bf16x8;
typedef __attribute__((ext_vector_type(4))) short bf16x4;
typedef __attribute__((ext_vector_type(4))) float f32x4;
typedef __attribute__((ext_vector_type(16))) float f32x16;

// round-to-nearest-even fp32 -> bf16
__device__ __forceinline__ unsigned short f2bf(float f) {
  unsigned u = __float_as_uint(f);
  return (unsigned short)((u + 0x7FFFu + ((u >> 16) & 1u)) >> 16);
}

// async 16B global -> LDS (lane i lands at ldsbase + i*16)
__device__ __forceinline__ void async_copy16(const void* g, void* l) {
  __builtin_amdgcn_global_load_lds((const __attribute__((address_space(1))) unsigned*)g,
                                   (__attribute__((address_space(3))) unsigned*)l, 16, 0, 0);
}

// ---------------- P1: X fp32 -> bf16 ----------------
__global__ __launch_bounds__(256) void cvt_x_kernel(const float* __restrict__ X,
                                                    short* __restrict__ Xb) {
  const int i = blockIdx.x * 256 + threadIdx.x;  // 8 floats per thread
  const float4* p = (const float4*)X + (size_t)i * 2;
  const float4 a = p[0], b = p[1];
  bf16x8 v;
  v[0] = f2bf(a.x); v[1] = f2bf(a.y); v[2] = f2bf(a.z); v[3] = f2bf(a.w);
  v[4] = f2bf(b.x); v[5] = f2bf(b.y); v[6] = f2bf(b.z); v[7] = f2bf(b.w);
  *((bf16x8*)Xb + i) = v;
}

// ---------------- P2: dequant Q[K][N] int32 -> Wt[N][K] bf16 (transposed) ----------------
// 256k x 128n tile per block, 512 threads; full-line reads/writes.
constexpr int DQ_STRIDE = 264;  // 256 + 8 pad shorts; 16B-aligned rows
__global__ __launch_bounds__(512) void dequant_w_kernel(const int* __restrict__ Q,
                                                        const float* __restrict__ S,
                                                        short* __restrict__ Wt) {
  __shared__ short Ls[128 * DQ_STRIDE];  // [n][k]
  const int k0 = blockIdx.x * 256;
  const int n0 = blockIdx.y * 128;
  const int t  = threadIdx.x;

  const int n4  = (t & 31) * 4;   // 0..124
  const int rbi = (t >> 5) * 4;   // 0..60
#pragma unroll
  for (int kc = 0; kc < 4; ++kc) {
    const int g  = (k0 >> 6) + kc;  // GROUP == 64
    const int kb = k0 + kc * 64 + rbi;
    const float4 s4 = *(const float4*)(S + (size_t)g * NDIM + n0 + n4);
    int4 q[4];
#pragma unroll
    for (int i = 0; i < 4; ++i)
      q[i] = *(const int4*)(Q + (size_t)(kb + i) * NDIM + n0 + n4);
    short* lp = &Ls[n4 * DQ_STRIDE + kc * 64 + rbi];
    bf16x4 v;
    v[0] = (short)f2bf((float)(q[0].x - 8) * s4.x);
    v[1] = (short)f2bf((float)(q[1].x - 8) * s4.x);
    v[2] = (short)f2bf((float)(q[2].x - 8) * s4.x);
    v[3] = (short)f2bf((float)(q[3].x - 8) * s4.x);
    *(bf16x4*)(lp + 0 * DQ_STRIDE) = v;
    v[0] = (short)f2bf((float)(q[0].y - 8) * s4.y);
    v[1] = (short)f2bf((float)(q[1].y - 8) * s4.y);
    v[2] = (short)f2bf((float)(q[2].y - 8) * s4.y);
    v[3] = (short)f2bf((float)(q[3].y - 8) * s4.y);
    *(bf16x4*)(lp + 1 * DQ_STRIDE) = v;
    v[0] = (short)f2bf((float)(q[0].z - 8) * s4.z);
    v[1] = (short)f2bf((float)(q[1].z - 8) * s4.z);
    v[2] = (short)f2bf((float)(q[2].z - 8) * s4.z);
    v[3] = (short)f2bf((float)(q[3].z - 8) * s4.z);
    *(bf16x4*)(lp + 2 * DQ_STRIDE) = v;
    v[0] = (short)f2bf((float)(q[0].w - 8) * s4.w);
    v[1] = (short)f2bf((float)(q[1].w - 8) * s4.w);
    v[2] = (short)f2bf((float)(q[2].w - 8) * s4.w);
    v[3] = (short)f2bf((float)(q[3].w - 8) * s4.w);
    *(bf16x4*)(lp + 3 * DQ_STRIDE) = v;
  }
  __syncthreads();

  const int c = (t & 7) * 8;  // 0..56 shorts
#pragma unroll
  for (int p = 0; p < 2; ++p) {
    const int nr = (t >> 3) + p * 64;  // 0..127
    const short* lr = &Ls[nr * DQ_STRIDE + c];
    short* wp = Wt + (size_t)(n0 + nr) * KDIM + k0 + c;
#pragma unroll
    for (int r = 0; r < 4; ++r)
      *(bf16x8*)(wp + r * 64) = *(const bf16x8*)(lr + r * 64);
  }
}

// ---------------- GEMM v3: Xb[M][K] x Wt[N][K] -> Out[M][N] ----------------
// Proven 2-barrier skeleton (128x128 tile, 256 thr, 32 KiB LDS) UNCHANGED.
// Changes vs v1:
//  (a) MFMA 16x16x32 -> 32x32x16 (same FLOPs, -17% issue cycles, higher pipe
//      ceiling). Per wave: 2x2 tiles of 32x32, acc f32x16 each.
//      C/D layout (m74/m101): col=lane&31, row=(reg&3)+8*(reg>>2)+4*(lane>>5).
//  (b) T1 XCD-bijective block swizzle (grid 3584 = 8*448): each Wt 128-row
//      panel's 32 m-blocks land on ONE XCD -> panel fetched into one L2, not 8.
__global__ __launch_bounds__(256, 2)
void gemm_bf16tt(const short* __restrict__ Xb, const short* __restrict__ Wt,
                 float* __restrict__ Out) {
  __shared__ short As[128 * 64];
  __shared__ short Bs[128 * 64];

  // XCD swizzle: lin in dispatch order (x fastest); 448 blocks per XCD chunk,
  // within a chunk swz sweeps bm fastest (32 m-blocks share one bn panel).
  const int lin = blockIdx.y * gridDim.x + blockIdx.x;
  const int swz = (lin & 7) * 448 + (lin >> 3);  // bijective: 3584 % 8 == 0
  const int bm = (swz & 31) * 128;
  const int bn = (swz >> 5) * 128;

  const int tid = threadIdx.x, lane = tid & 63, wave = tid >> 6;
  const int wm = (wave & 1) * 64, wn = (wave >> 1) * 64;
  const int l32 = lane & 31, khalf = lane >> 5;
  const int lx = l32 & 7;  // row&7 for fragment rows (wm/wn/i*32 are mult of 32)

  f32x16 acc[2][2];
#pragma unroll
  for (int i = 0; i < 2; ++i)
#pragma unroll
    for (int j = 0; j < 2; ++j)
#pragma unroll
      for (int r = 0; r < 16; ++r) acc[i][j][r] = 0.f;

  // staging: chunk (p*256+tid) -> LDS row p*32 + (tid>>3), slot tid&7
  // global k-chunk is XOR-swizzled: kof = ((tid&7) ^ (row&7)) * 8
  const int row0 = tid >> 3;
  const int kof  = (((tid & 7) ^ (row0 & 7))) * 8;
  const size_t aoff = (size_t)(bm + row0) * KDIM + kof;
  const size_t boff = (size_t)(bn + row0) * KDIM + kof;
  short* const la = &As[(wave * 64) * 8];  // wave-uniform base
  short* const lb = &Bs[(wave * 64) * 8];

  for (int kt = 0; kt < KDIM / 64; ++kt) {
    const int k0 = kt * 64;
    __syncthreads();  // previous tile's compute done
#pragma unroll
    for (int p = 0; p < 4; ++p) {
      async_copy16(Xb + aoff + (size_t)p * 32 * KDIM + k0, la + p * 2048);
      async_copy16(Wt + boff + (size_t)p * 32 * KDIM + k0, lb + p * 2048);
    }
    __syncthreads();  // staging complete

#pragma unroll
    for (int kk = 0; kk < 64; kk += 16) {
      const int ch = (kk >> 3) + khalf;  // k-chunk index 0..7 for this lane
      const int sl = (ch ^ lx) << 3;     // swizzled slot -> short offset
      bf16x8 af[2], bfr[2];
#pragma unroll
      for (int i = 0; i < 2; ++i)
        af[i] = *(const bf16x8*)&As[(wm + i * 32 + l32) * 64 + sl];
#pragma unroll
      for (int j = 0; j < 2; ++j)
        bfr[j] = *(const bf16x8*)&Bs[(wn + j * 32 + l32) * 64 + sl];
#pragma unroll
      for (int i = 0; i < 2; ++i)
#pragma unroll
        for (int j = 0; j < 2; ++j)
          acc[i][j] = __builtin_amdgcn_mfma_f32_32x32x16_bf16(af[i], bfr[j], acc[i][j], 0, 0, 0);
    }
  }

  // epilogue: col = lane&31, row = (reg&3) + 8*(reg>>2) + 4*khalf
#pragma unroll
  for (int i = 0; i < 2; ++i) {
#pragma unroll
    for (int j = 0; j < 2; ++j) {
      const int col = bn + wn + j * 32 + l32;
#pragma unroll
      for (int r = 0; r < 16; ++r) {
        const int row = bm + wm + i * 32 + (r & 3) + 8 * (r >> 2) + 4 * khalf;
        Out[(size_t)row * NDIM + col] = acc[i][j][r];
      }
    }
  }
}

// ---------------- fallback (fused, used only if ws too small) ----------------
constexpr int BKP = 72;
__global__ __launch_bounds__(256, 2)
void marlin_int4_gemm(const float* __restrict__ X, const int* __restrict__ Q,
                      const float* __restrict__ S, float* __restrict__ Out) {
  __shared__ short As[128 * BKP];
  __shared__ short Bs[128 * BKP];
  const int bm = blockIdx.x * 128, bn = blockIdx.y * 128;
  const int tid = threadIdx.x, lane = tid & 63, wave = tid >> 6;
  const int wm = (wave & 1) * 64, wn = (wave >> 1) * 64;
  const int quad = lane >> 4, l16 = lane & 15;
  const int nB = tid & 127, krB = (tid >> 7) * 32;
  f32x4 acc[4][4];
#pragma unroll
  for (int i = 0; i < 4; ++i)
#pragma unroll
    for (int j = 0; j < 4; ++j) acc[i][j] = (f32x4){0.f, 0.f, 0.f, 0.f};
  for (int kt = 0; kt < KDIM / 64; ++kt) {
    const int k0 = kt * 64;
    const float s = S[kt * NDIM + bn + nB];
    const float bias = -8.0f * s;
    __syncthreads();
#pragma unroll
    for (int i = 0; i < 8; ++i) {
      const int idx4 = tid + (i << 8);
      const int row = idx4 >> 4, col = (idx4 & 15) << 2;
      const float4 v = *(const float4*)(X + (size_t)(bm + row) * KDIM + k0 + col);
      ushort4 b;
      b.x = f2bf(v.x); b.y = f2bf(v.y); b.z = f2bf(v.z); b.w = f2bf(v.w);
      *(ushort4*)(&As[row * BKP + col]) = b;
    }
    unsigned short wb[32];
#pragma unroll
    for (int j = 0; j < 32; ++j) {
      const int qv = Q[(size_t)(k0 + krB + j) * NDIM + bn + nB];
      wb[j] = f2bf((float)qv * s + bias);
    }
    {
      short* brow = &Bs[nB * BKP + krB];
#pragma unroll
      for (int c = 0; c < 4; ++c) {
        bf16x8 v;
#pragma unroll
        for (int e = 0; e < 8; ++e) v[e] = (short)wb[c * 8 + e];
        *(bf16x8*)(brow + c * 8) = v;
      }
    }
    __syncthreads();
#pragma unroll
    for (int kk = 0; kk < 64; kk += 32) {
      bf16x8 af[4], bfr[4];
#pragma unroll
      for (int i = 0; i < 4; ++i)
        af[i] = *(const bf16x8*)&As[(wm + i * 16 + l16) * BKP + kk + quad * 8];
#pragma unroll
      for (int j = 0; j < 4; ++j)
        bfr[j] = *(const bf16x8*)&Bs[(wn + j * 16 + l16) * BKP + kk + quad * 8];
#pragma unroll
      for (int i = 0; i < 4; ++i)
#pragma unroll
        for (int j = 0; j < 4; ++j)
          acc[i][j] = __builtin_amdgcn_mfma_f32_16x16x32_bf16(af[i], bfr[j], acc[i][j], 0, 0, 0);
    }
  }
#pragma unroll
  for (int i = 0; i < 4; ++i) {
    const int r0 = bm + wm + i * 16 + quad * 4;
#pragma unroll
    for (int j = 0; j < 4; ++j) {
      const int col = bn + wn + j * 16 + l16;
#pragma unroll
      for (int r = 0; r < 4; ++r)
        Out[(size_t)(r0 + r) * NDIM + col] = acc[i][j][r];
    }
  }
}

extern "C" void kernel_launch(void* const* d_in, const int* in_sizes, int n_in,
                              void* d_out, int out_size, void* d_ws, size_t ws_size,
                              hipStream_t stream) {
  const float* X = (const float*)d_in[0];
  const int*   Q = (const int*)d_in[1];
  const float* S = (const float*)d_in[2];
  float* Out = (float*)d_out;

  const size_t xb_elems = (size_t)MDIM * KDIM;
  const size_t wt_elems = (size_t)NDIM * KDIM;
  const size_t need = (xb_elems + wt_elems) * sizeof(short);

  if (ws_size >= need) {
    short* Xb = (short*)d_ws;
    short* Wt = Xb + xb_elems;
    cvt_x_kernel<<<(int)(xb_elems / 8 / 256), 256, 0, stream>>>(X, Xb);
    dequant_w_kernel<<<dim3(KDIM / 256, NDIM / 128), 512, 0, stream>>>(Q, S, Wt);
    gemm_bf16tt<<<dim3(MDIM / 128, NDIM / 128), 256, 0, stream>>>(Xb, Wt, Out);
  } else {
    marlin_int4_gemm<<<dim3(MDIM / 128, NDIM / 128), 256, 0, stream>>>(X, Q, S, Out);
  }
}

// Round 5
// 880.466 us; speedup vs baseline: 1.0844x; 1.0844x over previous
//
#include <hip/hip_runtime.h>

#define MDIM 4096
#define KDIM 4096
#define NDIM 14336

typedef __attribute__((ext_vector_type(8))) short bf16x8;
typedef __attribute__((ext_vector_type(4))) short bf16x4;
typedef __attribute__((ext_vector_type(4))) float f32x4;

// round-to-nearest-even fp32 -> bf16
__device__ __forceinline__ unsigned short f2bf(float f) {
  unsigned u = __float_as_uint(f);
  return (unsigned short)((u + 0x7FFFu + ((u >> 16) & 1u)) >> 16);
}

// async 16B global -> LDS (lane i lands at ldsbase + i*16)
__device__ __forceinline__ void async_copy16(const void* g, void* l) {
  __builtin_amdgcn_global_load_lds((const __attribute__((address_space(1))) unsigned*)g,
                                   (__attribute__((address_space(3))) unsigned*)l, 16, 0, 0);
}

// inline-asm LDS read: escapes the compiler's conservative vmcnt drain between
// global_load_lds (LDS write, unknown region) and a C++ LDS load. [rule 18:
// follow the lgkmcnt(0) wait with sched_barrier(0) before consuming MFMAs]
__device__ __forceinline__ bf16x8 ds_read_b128(const short* p) {
  bf16x8 r;
  auto lp = (const __attribute__((address_space(3))) short*)p;
  asm volatile("ds_read_b128 %0, %1" : "=v"(r) : "v"(lp));
  return r;
}

// ---------------- P1: X fp32 -> bf16 ----------------
__global__ __launch_bounds__(256) void cvt_x_kernel(const float* __restrict__ X,
                                                    short* __restrict__ Xb) {
  const int i = blockIdx.x * 256 + threadIdx.x;  // 8 floats per thread
  const float4* p = (const float4*)X + (size_t)i * 2;
  const float4 a = p[0], b = p[1];
  bf16x8 v;
  v[0] = f2bf(a.x); v[1] = f2bf(a.y); v[2] = f2bf(a.z); v[3] = f2bf(a.w);
  v[4] = f2bf(b.x); v[5] = f2bf(b.y); v[6] = f2bf(b.z); v[7] = f2bf(b.w);
  *((bf16x8*)Xb + i) = v;
}

// ---------------- P2: dequant Q[K][N] int32 -> Wt[N][K] bf16 (transposed) ----------------
constexpr int DQ_STRIDE = 264;  // 256 + 8 pad shorts; 16B-aligned rows
__global__ __launch_bounds__(512) void dequant_w_kernel(const int* __restrict__ Q,
                                                        const float* __restrict__ S,
                                                        short* __restrict__ Wt) {
  __shared__ short Ls[128 * DQ_STRIDE];  // [n][k]
  const int k0 = blockIdx.x * 256;
  const int n0 = blockIdx.y * 128;
  const int t  = threadIdx.x;

  const int n4  = (t & 31) * 4;   // 0..124
  const int rbi = (t >> 5) * 4;   // 0..60
#pragma unroll
  for (int kc = 0; kc < 4; ++kc) {
    const int g  = (k0 >> 6) + kc;  // GROUP == 64
    const int kb = k0 + kc * 64 + rbi;
    const float4 s4 = *(const float4*)(S + (size_t)g * NDIM + n0 + n4);
    int4 q[4];
#pragma unroll
    for (int i = 0; i < 4; ++i)
      q[i] = *(const int4*)(Q + (size_t)(kb + i) * NDIM + n0 + n4);
    short* lp = &Ls[n4 * DQ_STRIDE + kc * 64 + rbi];
    bf16x4 v;
    v[0] = (short)f2bf((float)(q[0].x - 8) * s4.x);
    v[1] = (short)f2bf((float)(q[1].x - 8) * s4.x);
    v[2] = (short)f2bf((float)(q[2].x - 8) * s4.x);
    v[3] = (short)f2bf((float)(q[3].x - 8) * s4.x);
    *(bf16x4*)(lp + 0 * DQ_STRIDE) = v;
    v[0] = (short)f2bf((float)(q[0].y - 8) * s4.y);
    v[1] = (short)f2bf((float)(q[1].y - 8) * s4.y);
    v[2] = (short)f2bf((float)(q[2].y - 8) * s4.y);
    v[3] = (short)f2bf((float)(q[3].y - 8) * s4.y);
    *(bf16x4*)(lp + 1 * DQ_STRIDE) = v;
    v[0] = (short)f2bf((float)(q[0].z - 8) * s4.z);
    v[1] = (short)f2bf((float)(q[1].z - 8) * s4.z);
    v[2] = (short)f2bf((float)(q[2].z - 8) * s4.z);
    v[3] = (short)f2bf((float)(q[3].z - 8) * s4.z);
    *(bf16x4*)(lp + 2 * DQ_STRIDE) = v;
    v[0] = (short)f2bf((float)(q[0].w - 8) * s4.w);
    v[1] = (short)f2bf((float)(q[1].w - 8) * s4.w);
    v[2] = (short)f2bf((float)(q[2].w - 8) * s4.w);
    v[3] = (short)f2bf((float)(q[3].w - 8) * s4.w);
    *(bf16x4*)(lp + 3 * DQ_STRIDE) = v;
  }
  __syncthreads();

  const int c = (t & 7) * 8;  // 0..56 shorts
#pragma unroll
  for (int p = 0; p < 2; ++p) {
    const int nr = (t >> 3) + p * 64;  // 0..127
    const short* lr = &Ls[nr * DQ_STRIDE + c];
    short* wp = Wt + (size_t)(n0 + nr) * KDIM + k0 + c;
#pragma unroll
    for (int r = 0; r < 4; ++r)
      *(bf16x8*)(wp + r * 64) = *(const bf16x8*)(lr + r * 64);
  }
}

// ---------------- GEMM v5: 256x256 8-phase pipelined (T2+T3+T4+T5) ----------------
// 8 waves (2M x 4N, wave tile 128x64 = m201 geometry), BK=64, double-buffered
// 128 KiB LDS, derived-waits schedule:
//   per K-tile kt, 4 phases (quadrants). Phase 0:
//     s_barrier (WAR: all waves done reading buf[nxt] in tile kt-1)
//     stage group0 of tile kt+1 -> buf[nxt]        (2 gload_lds)
//     s_waitcnt vmcnt(2)  (drains tile kt's 8 ops; kt+1's 2 stay in flight)
//     s_barrier (RAW: everyone's tile-kt loads landed)
//     asm ds_read x12 ; lgkmcnt(0); sched_barrier; setprio(1); 16 MFMA; setprio(0)
//   Phases 1..3: stage group p of kt+1, then read+MFMA quadrant p.
// Fragment/swizzle algebra is the verified v1 16x16x32 pattern (0 conflicts),
// scaled: slot s of row r holds k-chunk s^(r&7); read slot = ch^(l16&7).
__global__ __launch_bounds__(512, 1)
void gemm_bf16tt(const short* __restrict__ Xb, const short* __restrict__ Wt,
                 float* __restrict__ Out) {
  __shared__ short As[2][256 * 64];  // 64 KiB
  __shared__ short Bs[2][256 * 64];  // 64 KiB

  const int bm = blockIdx.x * 256;  // 16 blocks
  const int bn = blockIdx.y * 256;  // 56 blocks
  const int tid = threadIdx.x, lane = tid & 63, wave = tid >> 6;
  const int wr = wave >> 2;   // 0..1  (M half: 128 rows)
  const int wc = wave & 3;    // 0..3  (N quarter: 64 cols)
  const int quad = lane >> 4, l16 = lane & 15;
  const int lx = l16 & 7;

  f32x4 acc[8][4];
#pragma unroll
  for (int i = 0; i < 8; ++i)
#pragma unroll
    for (int j = 0; j < 4; ++j) acc[i][j] = (f32x4){0.f, 0.f, 0.f, 0.f};

  // staging: per group (128 rows x 64 k = 16 KiB), thread covers rows
  // p2*64 + (tid>>3), slot tid&7, two loads (p2 = 0,1). Pre-swizzled source k.
  const int row0 = tid >> 3;                        // 0..63
  const int kof  = ((tid & 7) ^ (row0 & 7)) * 8;
  const size_t aoff = (size_t)(bm + row0) * KDIM + kof;
  const size_t boff = (size_t)(bn + row0) * KDIM + kof;
  const int ldst_off = wave * 8 * 64;  // wave-uniform: 8 rows per wave per call

  // groups: 0 = A rows[0,128), 1 = A rows[128,256), 2 = B rows[0,128), 3 = B[128,256)
#define STAGE_G(buf, g, kt1)                                                          \
  do {                                                                                \
    const short* gsrc = (((g) < 2) ? (Xb + aoff) : (Wt + boff)) +                     \
                        (size_t)((g) & 1) * 128 * KDIM + (size_t)(kt1) * 64;          \
    short* ldst = (((g) < 2) ? As[buf] : Bs[buf]) + (((g) & 1) * 128) * 64 + ldst_off;\
    async_copy16(gsrc, ldst);                                                         \
    async_copy16(gsrc + (size_t)64 * KDIM, ldst + 64 * 64);                           \
  } while (0)

  // phase compute: quadrant p -> (mh = p>>1, nh = p&1)
#define PHASE_COMPUTE(cur, mh, nh)                                                    \
  do {                                                                                \
    const short* Ab = As[cur];                                                        \
    const short* Bb = Bs[cur];                                                        \
    bf16x8 af[4][2], bv[2][2];                                                        \
    _Pragma("unroll") for (int s = 0; s < 2; ++s) {                                   \
      const int sl = (((s * 4 + quad)) ^ lx) << 3;                                    \
      _Pragma("unroll") for (int i = 0; i < 4; ++i)                                   \
        af[i][s] = ds_read_b128(&Ab[(wr * 128 + ((mh) * 4 + i) * 16 + l16) * 64 + sl]);\
      _Pragma("unroll") for (int j = 0; j < 2; ++j)                                   \
        bv[j][s] = ds_read_b128(&Bb[(wc * 64 + ((nh) * 2 + j) * 16 + l16) * 64 + sl]);\
    }                                                                                 \
    asm volatile("s_waitcnt lgkmcnt(0)" ::: "memory");                                \
    __builtin_amdgcn_sched_barrier(0);                                                \
    __builtin_amdgcn_s_setprio(1);                                                    \
    _Pragma("unroll") for (int i = 0; i < 4; ++i)                                     \
      _Pragma("unroll") for (int j = 0; j < 2; ++j)                                   \
        _Pragma("unroll") for (int s = 0; s < 2; ++s)                                 \
          acc[(mh) * 4 + i][(nh) * 2 + j] = __builtin_amdgcn_mfma_f32_16x16x32_bf16(  \
              af[i][s], bv[j][s], acc[(mh) * 4 + i][(nh) * 2 + j], 0, 0, 0);          \
    __builtin_amdgcn_s_setprio(0);                                                    \
  } while (0)

  constexpr int NT = KDIM / 64;  // 64

  // prologue: stage all 4 groups of tile 0 into buf 0 (8 vm ops in flight)
#pragma unroll
  for (int g = 0; g < 4; ++g) STAGE_G(0, g, 0);

  for (int kt = 0; kt < NT; ++kt) {
    const int cur = kt & 1, nxt = cur ^ 1;
    const bool pre = (kt + 1 < NT);
    // ---- phase 0 ----
    __builtin_amdgcn_s_barrier();  // WAR: buf[nxt] reads (tile kt-1) done chip... block-wide
    __builtin_amdgcn_sched_barrier(0);
    if (pre) {
      STAGE_G(nxt, 0, kt + 1);
      asm volatile("s_waitcnt vmcnt(2)" ::: "memory");  // drain tile kt's 8 loads
    } else {
      asm volatile("s_waitcnt vmcnt(0)" ::: "memory");
    }
    __builtin_amdgcn_s_barrier();  // RAW: all waves' tile-kt loads are in LDS
    __builtin_amdgcn_sched_barrier(0);
    PHASE_COMPUTE(cur, 0, 0);
    // ---- phase 1 ----
    if (pre) STAGE_G(nxt, 1, kt + 1);
    PHASE_COMPUTE(cur, 0, 1);
    // ---- phase 2 ----
    if (pre) STAGE_G(nxt, 2, kt + 1);
    PHASE_COMPUTE(cur, 1, 0);
    // ---- phase 3 ----
    if (pre) STAGE_G(nxt, 3, kt + 1);
    PHASE_COMPUTE(cur, 1, 1);
  }
#undef STAGE_G
#undef PHASE_COMPUTE

  // epilogue: C/D layout col=lane&15, row=quad*4+reg (16x16 verified)
#pragma unroll
  for (int i = 0; i < 8; ++i) {
    const int r0 = bm + wr * 128 + i * 16 + quad * 4;
#pragma unroll
    for (int j = 0; j < 4; ++j) {
      const int col = bn + wc * 64 + j * 16 + l16;
#pragma unroll
      for (int r = 0; r < 4; ++r)
        Out[(size_t)(r0 + r) * NDIM + col] = acc[i][j][r];
    }
  }
}

// ---------------- fallback (fused, used only if ws too small) ----------------
constexpr int BKP = 72;
__global__ __launch_bounds__(256, 2)
void marlin_int4_gemm(const float* __restrict__ X, const int* __restrict__ Q,
                      const float* __restrict__ S, float* __restrict__ Out) {
  __shared__ short As[128 * BKP];
  __shared__ short Bs[128 * BKP];
  const int bm = blockIdx.x * 128, bn = blockIdx.y * 128;
  const int tid = threadIdx.x, lane = tid & 63, wave = tid >> 6;
  const int wm = (wave & 1) * 64, wn = (wave >> 1) * 64;
  const int quad = lane >> 4, l16 = lane & 15;
  const int nB = tid & 127, krB = (tid >> 7) * 32;
  f32x4 acc[4][4];
#pragma unroll
  for (int i = 0; i < 4; ++i)
#pragma unroll
    for (int j = 0; j < 4; ++j) acc[i][j] = (f32x4){0.f, 0.f, 0.f, 0.f};
  for (int kt = 0; kt < KDIM / 64; ++kt) {
    const int k0 = kt * 64;
    const float s = S[kt * NDIM + bn + nB];
    const float bias = -8.0f * s;
    __syncthreads();
#pragma unroll
    for (int i = 0; i < 8; ++i) {
      const int idx4 = tid + (i << 8);
      const int row = idx4 >> 4, col = (idx4 & 15) << 2;
      const float4 v = *(const float4*)(X + (size_t)(bm + row) * KDIM + k0 + col);
      ushort4 b;
      b.x = f2bf(v.x); b.y = f2bf(v.y); b.z = f2bf(v.z); b.w = f2bf(v.w);
      *(ushort4*)(&As[row * BKP + col]) = b;
    }
    unsigned short wb[32];
#pragma unroll
    for (int j = 0; j < 32; ++j) {
      const int qv = Q[(size_t)(k0 + krB + j) * NDIM + bn + nB];
      wb[j] = f2bf((float)qv * s + bias);
    }
    {
      short* brow = &Bs[nB * BKP + krB];
#pragma unroll
      for (int c = 0; c < 4; ++c) {
        bf16x8 v;
#pragma unroll
        for (int e = 0; e < 8; ++e) v[e] = (short)wb[c * 8 + e];
        *(bf16x8*)(brow + c * 8) = v;
      }
    }
    __syncthreads();
#pragma unroll
    for (int kk = 0; kk < 64; kk += 32) {
      bf16x8 af[4], bfr[4];
#pragma unroll
      for (int i = 0; i < 4; ++i)
        af[i] = *(const bf16x8*)&As[(wm + i * 16 + l16) * BKP + kk + quad * 8];
#pragma unroll
      for (int j = 0; j < 4; ++j)
        bfr[j] = *(const bf16x8*)&Bs[(wn + j * 16 + l16) * BKP + kk + quad * 8];
#pragma unroll
      for (int i = 0; i < 4; ++i)
#pragma unroll
        for (int j = 0; j < 4; ++j)
          acc[i][j] = __builtin_amdgcn_mfma_f32_16x16x32_bf16(af[i], bfr[j], acc[i][j], 0, 0, 0);
    }
  }
#pragma unroll
  for (int i = 0; i < 4; ++i) {
    const int r0 = bm + wm + i * 16 + quad * 4;
#pragma unroll
    for (int j = 0; j < 4; ++j) {
      const int col = bn + wn + j * 16 + l16;
#pragma unroll
      for (int r = 0; r < 4; ++r)
        Out[(size_t)(r0 + r) * NDIM + col] = acc[i][j][r];
    }
  }
}

extern "C" void kernel_launch(void* const* d_in, const int* in_sizes, int n_in,
                              void* d_out, int out_size, void* d_ws, size_t ws_size,
                              hipStream_t stream) {
  const float* X = (const float*)d_in[0];
  const int*   Q = (const int*)d_in[1];
  const float* S = (const float*)d_in[2];
  float* Out = (float*)d_out;

  const size_t xb_elems = (size_t)MDIM * KDIM;
  const size_t wt_elems = (size_t)NDIM * KDIM;
  const size_t need = (xb_elems + wt_elems) * sizeof(short);

  if (ws_size >= need) {
    short* Xb = (short*)d_ws;
    short* Wt = Xb + xb_elems;
    cvt_x_kernel<<<(int)(xb_elems / 8 / 256), 256, 0, stream>>>(X, Xb);
    dequant_w_kernel<<<dim3(KDIM / 256, NDIM / 128), 512, 0, stream>>>(Q, S, Wt);
    gemm_bf16tt<<<dim3(MDIM / 256, NDIM / 256), 512, 0, stream>>>(Xb, Wt, Out);
  } else {
    marlin_int4_gemm<<<dim3(MDIM / 128, NDIM / 128), 256, 0, stream>>>(X, Q, S, Out);
  }
}